// Round 1
// baseline (95.254 us; speedup 1.0000x reference)
//
#include <hip/hip_runtime.h>

// BayesPosLinear: out[s,b,o] = sum_i input[s,b,i] * exp(w_mu[o,i] + softplus(w_std_eta[o,i])*eps_w[b,o,i])
//                 + (b_mu[o] + softplus(b_std_eta[o])*eps_b[b,o])
// plus KL(w), KL(b) scalars.
// S=16, B=32, IN=1024, OUT=1024. Memory-bound on eps_w (134 MB).

constexpr int S_ = 16, B_ = 32, IN_ = 1024, OUT_ = 1024;

__device__ __forceinline__ float softplus_f(float x) {
    // stable: max(x,0) + log1p(exp(-|x|))
    float e = __expf(-fabsf(x));
    return fmaxf(x, 0.0f) + __logf(1.0f + e);
}

// ---------------- main batched-linear kernel ----------------
// grid: 2048 blocks (32 b x 64 o-tiles of 16), 256 threads (4 waves x 4 o each)
// XCD swizzle: blockIdx%8 picks the OUT-eighth -> each XCD's w_mu/w_std slice (1MB) is L2-resident.
__global__ __launch_bounds__(256) void bpl_main_kernel(
    const float* __restrict__ input,   // [S,B,IN]
    const float* __restrict__ w_mu,    // [OUT,IN]
    const float* __restrict__ w_eta,   // [OUT,IN]
    const float* __restrict__ b_mu,    // [OUT]
    const float* __restrict__ b_eta,   // [OUT]
    const float* __restrict__ eps_w,   // [B,OUT,IN]
    const float* __restrict__ eps_b,   // [B,OUT]
    float* __restrict__ out)           // [S,B,OUT]
{
    __shared__ float res[16][17];      // [s][o_local], padded

    const int blk  = blockIdx.x;
    const int xcd  = blk & 7;          // OUT-eighth -> XCD-local L2 working set
    const int rest = blk >> 3;
    const int b    = rest & 31;
    const int osub = rest >> 5;        // 0..7
    const int o_base = xcd * 128 + osub * 16;

    const int tid  = threadIdx.x;
    const int wid  = tid >> 6;
    const int lane = tid & 63;
    const int o0   = o_base + wid * 4;

    float acc[4][16];
    #pragma unroll
    for (int ot = 0; ot < 4; ++ot)
        #pragma unroll
        for (int s = 0; s < 16; ++s) acc[ot][s] = 0.0f;

    #pragma unroll
    for (int chunk = 0; chunk < 4; ++chunk) {
        const int i0 = chunk * 256 + lane * 4;   // lane-consecutive float4 -> 1KB/instr

        float4 in4[16];
        #pragma unroll
        for (int s = 0; s < 16; ++s)
            in4[s] = *reinterpret_cast<const float4*>(&input[(size_t)(s * B_ + b) * IN_ + i0]);

        #pragma unroll
        for (int ot = 0; ot < 4; ++ot) {
            const int o = o0 + ot;
            const float4 mu = *reinterpret_cast<const float4*>(&w_mu[(size_t)o * IN_ + i0]);
            const float4 et = *reinterpret_cast<const float4*>(&w_eta[(size_t)o * IN_ + i0]);
            const float4 ep = *reinterpret_cast<const float4*>(&eps_w[((size_t)b * OUT_ + o) * IN_ + i0]);

            const float w0 = __expf(fmaf(1e-6f + softplus_f(et.x), ep.x, mu.x));
            const float w1 = __expf(fmaf(1e-6f + softplus_f(et.y), ep.y, mu.y));
            const float w2 = __expf(fmaf(1e-6f + softplus_f(et.z), ep.z, mu.z));
            const float w3 = __expf(fmaf(1e-6f + softplus_f(et.w), ep.w, mu.w));

            #pragma unroll
            for (int s = 0; s < 16; ++s) {
                float a = acc[ot][s];
                a = fmaf(in4[s].x, w0, a);
                a = fmaf(in4[s].y, w1, a);
                a = fmaf(in4[s].z, w2, a);
                a = fmaf(in4[s].w, w3, a);
                acc[ot][s] = a;
            }
        }
    }

    // butterfly tree-reduce each of the 64 accumulators across the 64 lanes
    #pragma unroll
    for (int ot = 0; ot < 4; ++ot)
        #pragma unroll
        for (int s = 0; s < 16; ++s) {
            float v = acc[ot][s];
            #pragma unroll
            for (int off = 32; off > 0; off >>= 1) v += __shfl_xor(v, off, 64);
            acc[ot][s] = v;
        }

    // lane l takes value (ot = l>>4, s = l&15) -- static-indexed cndmask chain (no scratch)
    float mine = 0.0f;
    #pragma unroll
    for (int ot = 0; ot < 4; ++ot)
        #pragma unroll
        for (int s = 0; s < 16; ++s)
            mine = (lane == ot * 16 + s) ? acc[ot][s] : mine;

    res[lane & 15][wid * 4 + (lane >> 4)] = mine;
    __syncthreads();

    // coalesced store with fused bias: thread t -> (s = t>>4, o_local = t&15)
    const int s  = tid >> 4;
    const int ol = tid & 15;
    const int o  = o_base + ol;
    const float bias = fmaf(1e-6f + softplus_f(b_eta[o]), eps_b[(size_t)b * OUT_ + o], b_mu[o]);
    out[(size_t)(s * B_ + b) * OUT_ + o] = res[s][ol] + bias;
}

// ---------------- KL reduction kernel ----------------
// 1024 blocks x 256 threads; block k reduces w-row k (1024 elems, float4/thread).
// block 0 additionally reduces the 1024-elem bias KL.
__global__ __launch_bounds__(256) void bpl_kl_kernel(
    const float* __restrict__ w_mu, const float* __restrict__ w_eta,
    const float* __restrict__ b_mu, const float* __restrict__ b_eta,
    float* __restrict__ kl)            // kl[0]=kl_w, kl[1]=kl_b (pre-zeroed)
{
    __shared__ float red[4];
    const int tid  = threadIdx.x;
    const int wid  = tid >> 6;
    const int lane = tid & 63;

    const size_t base = (size_t)blockIdx.x * IN_ + tid * 4;
    const float4 mu = *reinterpret_cast<const float4*>(&w_mu[base]);
    const float4 et = *reinterpret_cast<const float4*>(&w_eta[base]);

    float local = 0.0f;
    {
        const float m[4] = {mu.x, mu.y, mu.z, mu.w};
        const float e[4] = {et.x, et.y, et.z, et.w};
        #pragma unroll
        for (int j = 0; j < 4; ++j) {
            const float sd = 1e-6f + softplus_f(e[j]);
            local += -__logf(sd) + 0.5f * fmaf(sd, sd, m[j] * m[j]) - 0.5f;
        }
    }
    #pragma unroll
    for (int off = 32; off > 0; off >>= 1) local += __shfl_xor(local, off, 64);
    if (lane == 0) red[wid] = local;
    __syncthreads();
    if (tid == 0) atomicAdd(&kl[0], red[0] + red[1] + red[2] + red[3]);

    if (blockIdx.x != 0) return;

    // kl_b: 1024 elems, 4 per thread
    float lb = 0.0f;
    #pragma unroll
    for (int j = 0; j < 4; ++j) {
        const int idx = tid * 4 + j;
        const float sd = 1e-6f + softplus_f(b_eta[idx]);
        const float m  = b_mu[idx];
        lb += -__logf(sd) + 0.5f * fmaf(sd, sd, m * m) - 0.5f;
    }
    #pragma unroll
    for (int off = 32; off > 0; off >>= 1) lb += __shfl_xor(lb, off, 64);
    __syncthreads();                 // tid0 finished reading red above
    if (lane == 0) red[wid] = lb;
    __syncthreads();
    if (tid == 0) atomicAdd(&kl[1], red[0] + red[1] + red[2] + red[3]);
}

extern "C" void kernel_launch(void* const* d_in, const int* in_sizes, int n_in,
                              void* d_out, int out_size, void* d_ws, size_t ws_size,
                              hipStream_t stream)
{
    const float* input = (const float*)d_in[0];
    const float* w_mu  = (const float*)d_in[1];
    const float* w_eta = (const float*)d_in[2];
    const float* b_mu  = (const float*)d_in[3];
    const float* b_eta = (const float*)d_in[4];
    const float* eps_w = (const float*)d_in[5];
    const float* eps_b = (const float*)d_in[6];

    float* out = (float*)d_out;
    float* kl  = out + (size_t)S_ * B_ * OUT_;   // offsets 524288, 524289

    hipMemsetAsync(kl, 0, 2 * sizeof(float), stream);
    bpl_kl_kernel<<<1024, 256, 0, stream>>>(w_mu, w_eta, b_mu, b_eta, kl);
    bpl_main_kernel<<<2048, 256, 0, stream>>>(input, w_mu, w_eta, b_mu, b_eta, eps_w, eps_b, out);
}